// Round 3
// baseline (1325.741 us; speedup 1.0000x reference)
//
#include <hip/hip_runtime.h>

#define N_BINS 15
#define A_BLOCKS 2048
#define B_BLOCKS 256

typedef float f4 __attribute__((ext_vector_type(4)));
typedef float f2 __attribute__((ext_vector_type(2)));

__device__ __forceinline__ float max4(f4 v) {
    return fmaxf(fmaxf(v[0], v[1]), fmaxf(v[2], v[3]));
}

// ---------------- Kernel A: per-row confidence + accuracy ----------------
// Each wave-iteration covers 8 rows = 4 KB CONTIGUOUS.
// Load t (t=0..3): f4 index = base*32 + t*64 + lane  ->  one 1 KB segment
// per instruction. Lanes 0-31 hold row base+2t, lanes 32-63 row base+2t+1
// (lane&31 = float4-column). Half-wave xor-shuffle reduction (masks 1..16
// never cross the 32-lane boundary).
__global__ __launch_bounds__(256) void ece_rowpass(
    const float* __restrict__ probs,
    const int* __restrict__ labels,
    const int* __restrict__ is_logit_p,
    f2* __restrict__ rowout,
    int n_rows)
{
    const int is_logit = *is_logit_p;   // uniform
    const int tid  = threadIdx.x;
    const int lane = tid & 63;
    const int wid  = tid >> 6;          // wave in block 0..3
    const int half = lane >> 5;         // 0 or 1
    const int col4 = lane & 31;         // float4 column within row

    const long long nr = n_rows;
    long long base = ((long long)blockIdx.x * 4 + wid) * 8;
    const long long bstride = (long long)gridDim.x * 32;

    const f4* __restrict__ pf4 = (const f4*)probs;

    for (; base < nr; base += bstride) {
        // clamp tail so rows cb..cb+7 are always legal; duplicate rows just
        // re-write identical values (idempotent, no atomics here).
        const long long cb = (base + 8 <= nr) ? base : (nr - 8);
        const f4* p = pf4 + cb * 32 + lane;
        const f4 v0 = __builtin_nontemporal_load(p);
        const f4 v1 = __builtin_nontemporal_load(p + 64);
        const f4 v2 = __builtin_nontemporal_load(p + 128);
        const f4 v3 = __builtin_nontemporal_load(p + 192);

#pragma unroll
        for (int t = 0; t < 4; ++t) {
            const f4 v = (t == 0) ? v0 : (t == 1) ? v1 : (t == 2) ? v2 : v3;
            const long long r = cb + 2 * t + half;

            // row max over the 32-lane half
            float m = max4(v);
            m = fmaxf(m, __shfl_xor(m, 1, 64));
            m = fmaxf(m, __shfl_xor(m, 2, 64));
            m = fmaxf(m, __shfl_xor(m, 4, 64));
            m = fmaxf(m, __shfl_xor(m, 8, 64));
            m = fmaxf(m, __shfl_xor(m, 16, 64));

            float conf;
            if (is_logit) {
                float s = (__expf(v[0] - m) + __expf(v[1] - m))
                        + (__expf(v[2] - m) + __expf(v[3] - m));
                s += __shfl_xor(s, 1, 64);
                s += __shfl_xor(s, 2, 64);
                s += __shfl_xor(s, 4, 64);
                s += __shfl_xor(s, 8, 64);
                s += __shfl_xor(s, 16, 64);
                conf = 1.0f / s;        // max softmax prob
            } else {
                conf = m;
            }

            // accuracy: does the label's element hold the row max?
            const int L = labels[r];
            const int c = L & 3;
            const float lv = (c == 0) ? v[0] : (c == 1) ? v[1]
                           : (c == 2) ? v[2] : v[3];
            const bool mine = (col4 == (L >> 2)) && (lv == m);
            const unsigned long long bal = __ballot(mine);
            const unsigned int hbits = half ? (unsigned int)(bal >> 32)
                                            : (unsigned int)bal;
            if (col4 == 0) {            // lane 0 -> row cb+2t, lane 32 -> cb+2t+1
                f2 o; o[0] = conf; o[1] = hbits ? 1.0f : 0.0f;
                rowout[r] = o;
            }
        }
    }
}

// ---------------- Kernel B: bin the (conf, acc) pairs ----------------
__global__ __launch_bounds__(256) void ece_binpass(
    const f2* __restrict__ rowout, float* __restrict__ bins, int n_rows)
{
    __shared__ float s_bins[4][3][17];
    const int tid = threadIdx.x;
    if (tid < 4 * 3 * 17) ((float*)s_bins)[tid] = 0.f;
    __syncthreads();

    const int wave = tid >> 6;
    for (long long i = (long long)blockIdx.x * 256 + tid; i < n_rows;
         i += (long long)gridDim.x * 256) {
        const f2 ca = rowout[i];
        int bin = (int)ceilf(ca[0] * (float)N_BINS) - 1;
        bin = bin < 0 ? 0 : (bin > N_BINS - 1 ? N_BINS - 1 : bin);
        atomicAdd(&s_bins[wave][0][bin], 1.0f);
        atomicAdd(&s_bins[wave][1][bin], ca[0]);
        atomicAdd(&s_bins[wave][2][bin], ca[1]);
    }

    __syncthreads();
    if (tid < 3 * N_BINS) {
        const int c = tid / N_BINS;
        const int b = tid - c * N_BINS;
        atomicAdd(&bins[tid], s_bins[0][c][b] + s_bins[1][c][b]
                            + s_bins[2][c][b] + s_bins[3][c][b]);
    }
}

// ---------------- Fallback fused kernel (round-1 best) ----------------
__global__ __launch_bounds__(256) void ece_fused(
    const float* __restrict__ probs,
    const int* __restrict__ labels,
    const int* __restrict__ is_logit_p,
    float* __restrict__ bins,
    int n_rows)
{
    __shared__ float s_bins[4][3][17];
    const int tid = threadIdx.x;
    if (tid < 4 * 3 * 17) ((float*)s_bins)[tid] = 0.f;
    __syncthreads();

    const int is_logit = *is_logit_p;
    const int lane = tid & 63;
    const int wave = tid >> 6;
    const int sub  = tid & 7;
    const int grp  = tid >> 3;

    long long row = (long long)blockIdx.x * 32 + grp;
    const long long stride = (long long)gridDim.x * 32;

    for (; row < n_rows; row += stride) {
        const f4* rp = (const f4*)probs + (size_t)row * 32 + sub;
        const f4 v0 = rp[0], v1 = rp[8], v2 = rp[16], v3 = rp[24];
        const int lab = labels[row];

        float m = fmaxf(fmaxf(max4(v0), max4(v1)), fmaxf(max4(v2), max4(v3)));
        m = fmaxf(m, __shfl_xor(m, 1, 64));
        m = fmaxf(m, __shfl_xor(m, 2, 64));
        m = fmaxf(m, __shfl_xor(m, 4, 64));

        float conf;
        if (is_logit) {
            float s = (__expf(v0[0]-m)+__expf(v0[1]-m))+(__expf(v0[2]-m)+__expf(v0[3]-m))
                    + (__expf(v1[0]-m)+__expf(v1[1]-m))+(__expf(v1[2]-m)+__expf(v1[3]-m))
                    + (__expf(v2[0]-m)+__expf(v2[1]-m))+(__expf(v2[2]-m)+__expf(v2[3]-m))
                    + (__expf(v3[0]-m)+__expf(v3[1]-m))+(__expf(v3[2]-m)+__expf(v3[3]-m));
            s += __shfl_xor(s, 1, 64);
            s += __shfl_xor(s, 2, 64);
            s += __shfl_xor(s, 4, 64);
            conf = 1.0f / s;
        } else {
            conf = m;
        }

        const int f = lab >> 2, c = lab & 3, k = f >> 3;
        f4 vk = (k == 0) ? v0 : (k == 1) ? v1 : (k == 2) ? v2 : v3;
        float lv = (c == 0) ? vk[0] : (c == 1) ? vk[1] : (c == 2) ? vk[2] : vk[3];
        const bool mine = ((f & 7) == sub) && (lv == m);
        const unsigned long long bal = __ballot(mine);

        if (sub == 0) {
            int bin = (int)ceilf(conf * (float)N_BINS) - 1;
            bin = bin < 0 ? 0 : (bin > N_BINS - 1 ? N_BINS - 1 : bin);
            const float acc = ((bal >> (lane & 56)) & 0xFFull) ? 1.0f : 0.0f;
            atomicAdd(&s_bins[wave][0][bin], 1.0f);
            atomicAdd(&s_bins[wave][1][bin], conf);
            atomicAdd(&s_bins[wave][2][bin], acc);
        }
    }

    __syncthreads();
    if (tid < 3 * N_BINS) {
        const int c = tid / N_BINS;
        const int b = tid - c * N_BINS;
        atomicAdd(&bins[tid], s_bins[0][c][b] + s_bins[1][c][b]
                            + s_bins[2][c][b] + s_bins[3][c][b]);
    }
}

__global__ void ece_final(const float* __restrict__ bins,
                          float* __restrict__ out, int n_rows)
{
    if (threadIdx.x == 0 && blockIdx.x == 0) {
        float ece = 0.f;
        for (int i = 0; i < N_BINS; ++i) {
            float c = bins[i];
            if (c > 0.f) {
                float gap = fabsf(bins[N_BINS + i] / c - bins[2 * N_BINS + i] / c);
                ece += gap * (c / (float)n_rows);
            }
        }
        out[0] = ece;
    }
}

extern "C" void kernel_launch(void* const* d_in, const int* in_sizes, int n_in,
                              void* d_out, int out_size, void* d_ws, size_t ws_size,
                              hipStream_t stream) {
    const float* probs    = (const float*)d_in[0];
    const int*   labels   = (const int*)d_in[1];
    const int*   is_logit = (const int*)d_in[2];
    float*       out      = (float*)d_out;
    float*       bins     = (float*)d_ws;
    const int n_rows = in_sizes[1];   // 2,000,000

    hipMemsetAsync(bins, 0, 3 * N_BINS * sizeof(float), stream);

    const size_t need = 1024 + (size_t)n_rows * sizeof(f2);
    if (ws_size >= need && n_rows >= 8) {
        f2* rowout = (f2*)((char*)d_ws + 1024);
        ece_rowpass<<<A_BLOCKS, 256, 0, stream>>>(probs, labels, is_logit,
                                                  rowout, n_rows);
        ece_binpass<<<B_BLOCKS, 256, 0, stream>>>(rowout, bins, n_rows);
    } else {
        ece_fused<<<1024, 256, 0, stream>>>(probs, labels, is_logit, bins, n_rows);
    }
    ece_final<<<1, 64, 0, stream>>>(bins, out, n_rows);
}